// Round 1
// baseline (269.808 us; speedup 1.0000x reference)
//
#include <hip/hip_runtime.h>
#include <math.h>

// B=2048 rows, L=16384, W=30 sliding mean of sigmoid(x)*mask, per-row max.
constexpr int Bn    = 2048;
constexpr int L     = 16384;
constexpr int W     = 30;
constexpr int NWIN  = L - W + 1;        // 16355
constexpr int NT    = 256;
constexpr int TILE  = 4096;             // window starts per block
constexpr int TPB   = L / TILE;         // 4 blocks per row
constexpr int NELEM = TILE + W - 1;     // 4125 staged elements
constexpr int SPT   = TILE / NT;        // 16 window starts per thread
constexpr int KLD   = TILE / (4 * NT);  // 4 float4 loads per thread per array

// LDS pad +1 float per 8. Read base for lane t: pidx(16t) = 18t ->
// 18t mod 32 = 16 distinct even residues per 32-lane phase, 2-way: free (m136).
// Offsets pidx(16t+c)-18t = c+(c>>3): compile-time.
__device__ __forceinline__ int pidx(int j) { return j + (j >> 3); }

__device__ __forceinline__ float sigp(float xv, float mv) {
    // m * 1/(1 + 2^(-x*log2(e))) : v_mul, v_exp, v_add, v_rcp, v_mul
    float t = -1.44269504089f * xv;
    float e;
    asm("v_exp_f32 %0, %1" : "=v"(e) : "v"(t));
    return mv * __builtin_amdgcn_rcpf(1.0f + e);
}

__global__ __launch_bounds__(NT, 4)   // cap 128 VGPR: room for 8 float4 in flight, no spill
void winmax_tile(const float* __restrict__ x,
                 const float* __restrict__ m,
                 float* __restrict__ out) {
    __shared__ float prob[NELEM + (NELEM >> 3) + 2];   // 4641 floats = 18.6 KiB

    const int b    = blockIdx.x;
    const int row  = b >> 2;            // TPB = 4
    const int tile = b & 3;
    const int t    = threadIdx.x;
    const int ts   = tile * TILE;

    const float* xr = x + (size_t)row * L + ts;
    const float* mr = m + (size_t)row * L + ts;
    const float4* x4 = (const float4*)xr;
    const float4* m4 = (const float4*)mr;

    // ---- Issue ALL global loads before any compute. VGPR_Count=24 in the
    // previous build proved the compiler fused load+use loops (only ~2 of 8
    // dwordx4 in flight -> MLP-starved at 1.4 TB/s HBM). sched_barrier(0)
    // pins the whole load pack (8x dwordx4 + halo) ahead of the sigp/LDS
    // phase; uses then drain vmcnt progressively.
    float4 xv[KLD], mv[KLD];
    #pragma unroll
    for (int k = 0; k < KLD; ++k) xv[k] = x4[k * NT + t];
    #pragma unroll
    for (int k = 0; k < KLD; ++k) mv[k] = m4[k * NT + t];

    // Halo: W-1=29 elements past the tile; zero-fill on the last tile.
    // sigp(0, 0) == 0, and truncated-window sums are subsets of the valid
    // window at L-30 (all terms >= 0), so zeros can never win the row max.
    float xh = 0.0f, mh = 0.0f;
    if (t < W - 1) {
        const int j = TILE + t;
        if (ts + j < L) { xh = xr[j]; mh = mr[j]; }
    }
    __builtin_amdgcn_sched_barrier(0);

    #pragma unroll
    for (int k = 0; k < KLD; ++k) {
        const int j = (k * NT + t) * 4;
        const int p = pidx(j);                          // j%4==0 -> contiguous 4
        prob[p + 0] = sigp(xv[k].x, mv[k].x);
        prob[p + 1] = sigp(xv[k].y, mv[k].y);
        prob[p + 2] = sigp(xv[k].z, mv[k].z);
        prob[p + 3] = sigp(xv[k].w, mv[k].w);
    }
    if (t < W - 1) {
        const int j = TILE + t;
        prob[pidx(j)] = sigp(xh, mh);                   // OOB lanes: mh=0 -> 0
    }
    __syncthreads();

    // ---- Sliding windows: thread t owns starts [16t, 16t+15], branch-free ----
    const int base = 18 * t;            // = pidx(16t)
    float keep[SPT - 1];
    float sum = 0.0f;
    #pragma unroll
    for (int c = 0; c < W; ++c) {       // offsets compile-time: c + (c>>3)
        const float v = prob[base + c + (c >> 3)];
        if (c < SPT - 1) keep[c] = v;
        sum += v;
    }
    float best = sum;
    #pragma unroll
    for (int i = 1; i < SPT; ++i) {
        const int c = W - 1 + i;
        sum += prob[base + c + (c >> 3)] - keep[i - 1];
        best = fmaxf(best, sum);
    }
    best *= (1.0f / W);

    // ---- Wave max-reduce, one atomic per wave (win_mean >= 0 -> uint order) ----
    #pragma unroll
    for (int off = 32; off > 0; off >>= 1)
        best = fmaxf(best, __shfl_down(best, off, 64));
    if ((t & 63) == 0)
        atomicMax((unsigned int*)(out + row), __float_as_uint(best));
}

extern "C" void kernel_launch(void* const* d_in, const int* in_sizes, int n_in,
                              void* d_out, int out_size, void* d_ws, size_t ws_size,
                              hipStream_t stream) {
    const float* x = (const float*)d_in[0];
    const float* m = (const float*)d_in[1];
    float* out = (float*)d_out;
    // out is poisoned 0xAA (negative float as bits) -> must zero for atomicMax.
    hipMemsetAsync(out, 0, Bn * sizeof(float), stream);
    winmax_tile<<<Bn * TPB, NT, 0, stream>>>(x, m, out);
}